// Round 10
// baseline (86.013 us; speedup 1.0000x reference)
//
#include <hip/hip_runtime.h>

typedef unsigned short ushort_t;
typedef __bf16 bf16x8 __attribute__((ext_vector_type(8)));
typedef float f32x4 __attribute__((ext_vector_type(4)));
typedef void __attribute__((address_space(1))) gvoid_t;
typedef void __attribute__((address_space(3))) lvoid_t;

__device__ __forceinline__ float bflo(unsigned u) { return __builtin_bit_cast(float, u << 16); }
__device__ __forceinline__ float bfhi(unsigned u) { return __builtin_bit_cast(float, u & 0xffff0000u); }
__device__ __forceinline__ unsigned f2bf_bits(float f) {
  unsigned u = __builtin_bit_cast(unsigned, f);
  return (u + 0x7fffu + ((u >> 16) & 1u)) >> 16;
}
__device__ __forceinline__ ushort_t f2bf(float f) { return (ushort_t)f2bf_bits(f); }

#define VMWAIT(N) asm volatile("s_waitcnt vmcnt(" #N ")" ::: "memory")
#define LGKM0 asm volatile("s_waitcnt lgkmcnt(0)" ::: "memory")

// ---------------- prep: weight (o,c,k) f32 -> wb[k][o][c] bf16 ----------------
__global__ __launch_bounds__(256) void k_prep_w(const float* __restrict__ w,
                                                ushort_t* __restrict__ wb) {
  const int idx = blockIdx.x * 256 + threadIdx.x;  // (o,c) pair, 65536 total
  const float* src = w + (size_t)idx * 9;
  #pragma unroll
  for (int k = 0; k < 9; ++k)
    wb[(k << 16) + idx] = f2bf(src[k]);
}

// ---------------- prep: x (b,c,h,w) f32 -> xt[b][h][w][c] bf16 ----------------
__global__ __launch_bounds__(256) void k_prep_x(const float* __restrict__ x,
                                                ushort_t* __restrict__ xt) {
  __shared__ ushort_t tile[64][68];
  const int bid = blockIdx.x;             // 4b * 4ct * 64pt = 1024
  const int b = bid >> 8;
  const int ct = (bid >> 6) & 3;
  const int pt = bid & 63;
  const int t = threadIdx.x;
  const float* xb = x + ((size_t)(b * 256 + ct * 64)) * 4096 + pt * 64;
  #pragma unroll
  for (int i = 0; i < 16; ++i) {
    const int idx = t + 256 * i;
    const int c_l = idx >> 6, p_l = idx & 63;
    tile[c_l][p_l] = f2bf(xb[(size_t)c_l * 4096 + p_l]);
  }
  __syncthreads();
  ushort_t* xo = xt + ((size_t)(b * 4096 + pt * 64)) * 256 + ct * 64;
  #pragma unroll
  for (int i = 0; i < 16; ++i) {
    const int idx = t + 256 * i;
    const int p_l = idx >> 6, c_l = idx & 63;
    xo[(size_t)p_l * 256 + c_l] = tile[c_l][p_l];
  }
}

// bilinear meta for one (h, w, tap)
struct SMeta {
  float w00, w01, w10, w11;
  int i00, i01, i10, i11;
};
__device__ __forceinline__ SMeta meta_for(int h, int gw, int k, float oy, float ox) {
  SMeta m;
  const float py = (float)(h - 1 + k / 3) + oy;
  const float px = (float)(gw - 1 + k % 3) + ox;
  const float fy = floorf(py), fx = floorf(px);
  const float ly = py - fy, lx = px - fx;
  const int iy0 = (int)fy, ix0 = (int)fx;
  const float vy0 = (iy0 >= 0 && iy0 < 64) ? 1.f : 0.f;
  const float vy1 = (iy0 >= -1 && iy0 < 63) ? 1.f : 0.f;
  const float vx0 = (ix0 >= 0 && ix0 < 64) ? 1.f : 0.f;
  const float vx1 = (ix0 >= -1 && ix0 < 63) ? 1.f : 0.f;
  m.w00 = (1.f - ly) * (1.f - lx) * vy0 * vx0;
  m.w01 = (1.f - ly) * lx * vy0 * vx1;
  m.w10 = ly * (1.f - lx) * vy1 * vx0;
  m.w11 = ly * lx * vy1 * vx1;
  const int cy0 = min(max(iy0, 0), 63), cy1 = min(max(iy0 + 1, 0), 63);
  const int cx0 = min(max(ix0, 0), 63), cx1 = min(max(ix0 + 1, 0), 63);
  m.i00 = (cy0 * 64 + cx0) * 256;
  m.i01 = (cy0 * 64 + cx1) * 256;
  m.i10 = (cy1 * 64 + cx0) * 256;
  m.i11 = (cy1 * 64 + cx1) * 256;
  return m;
}

__device__ __forceinline__ unsigned lerp_pack(unsigned a, unsigned b, unsigned c, unsigned d,
                                              float w00, float w01, float w10, float w11) {
  float lo = w00 * bflo(a) + w01 * bflo(b) + w10 * bflo(c) + w11 * bflo(d);
  float hi = w00 * bfhi(a) + w01 * bfhi(b) + w10 * bfhi(c) + w11 * bfhi(d);
  return f2bf_bits(lo) | (f2bf_bits(hi) << 16);
}

// ---------------- fused deform-sample + GEMM + GN partial stats ----------------
// PRODUCER/CONSUMER wave specialization. block = one output row (b,h): BM=64,
// BN=256, 8 waves (512 thr), grid=256. 18 periods of BK=128 (period p = tap
// p>>1, channel-half p&1). Waves 4-7 = producers: gathers (16 uint4), bilinear
// pack -> Abuf, B staging via global_load_lds (16/thread). Waves 0-3 =
// consumers: pure ds_read + MFMA (zero vmem), each owns one N-quarter x full
// BM (acc[4][4]). Each SIMD hosts 1 producer + 1 consumer wave in DIFFERENT
// pipes concurrently (R9 counters showed VALU+LDS+L2+MFMA summing, not
// overlapping, under lockstep phases). Sync per period: producers stage
// (p+1)-buffers, one self-healing VMWAIT(0) (retires own B-loads + any
// compiler spills; gathers compiler-waited), LGKM0, s_barrier (shared with
// consumers). Consumers never touch vmcnt. setprio(1) around MFMA (T5 - role
// diversity now exists). XCD swizzle: each XCD works one batch (L2-resident).
__global__ __launch_bounds__(512) void k_gemm(const float* __restrict__ off,
                                              const ushort_t* __restrict__ xt,
                                              const ushort_t* __restrict__ wb,
                                              float* __restrict__ y,
                                              float* __restrict__ stats) {
  __shared__ __attribute__((aligned(16))) ushort_t Abuf[2][2][64 * 64];   // [pbuf][chunk] 32KB
  __shared__ __attribute__((aligned(16))) ushort_t Bbuf[2][2][256 * 64];  // [pbuf][chunk] 128KB

  const int bid = blockIdx.x;                    // 256
  const int lb = ((bid & 7) << 5) | (bid >> 3);  // XCD-contiguous logical id
  const int b = lb >> 6;
  const int h = lb & 63;
  const int t = threadIdx.x;  // 0..511
  const int wave = t >> 6;
  const int lane = t & 63;
  const int wq = lane >> 4;
  const int wr = lane & 15;
  const bool prod = (wave >= 4);
  const int wn = wave & 3;       // consumer: N quarter
  const int pt = t & 255;        // producer: 0..255
  const int s_w = pt >> 2;       // producer: w column (0..63)
  const int c4 = pt & 3;         // producer: slice pair {c4, c4+4}

  const f32x4 zero = {0.f, 0.f, 0.f, 0.f};
  f32x4 acc[4][4];
  #pragma unroll
  for (int i = 0; i < 4; ++i)
    #pragma unroll
    for (int j = 0; j < 4; ++j) acc[i][j] = zero;

  const ushort_t* xtb = xt + (size_t)b * 4096 * 256;

  // producers: hoist all 18 offset values into registers
  float oy[9], ox[9];
  if (prod) {
    const float* offb = off + (size_t)b * 18 * 4096 + h * 64 + s_w;
    #pragma unroll
    for (int k = 0; k < 9; ++k) {
      oy[k] = offb[(2 * k) * 4096];
      ox[k] = offb[(2 * k + 1) * 4096];
    }
  }

  // Producer staging of period P (tap TAP, base col C0) into pbuf PB:
  //  - 16 uint4 gathers (4 groups: 2 chunks x 2 slice-groups x 4 corners)
  //  - 16 global_load_lds for the B tile (64KB: 2 chunks x 256 rows x 64 cols)
  //  - 4 packed A ds_write_b128 (compiler waits gathers; B stays in flight)
#define STAGE(TAP, C0, PB)                                                                     \
  {                                                                                            \
    const SMeta m = meta_for(h, s_w, (TAP), oy[(TAP)], ox[(TAP)]);                             \
    uint4 g[2][2][4];                                                                          \
    _Pragma("unroll") for (int ch_ = 0; ch_ < 2; ++ch_) {                                      \
      _Pragma("unroll") for (int sg_ = 0; sg_ < 2; ++sg_) {                                    \
        const int cc_ = (C0) + ch_ * 64 + (c4 + sg_ * 4) * 8;                                  \
        g[ch_][sg_][0] = *(const uint4*)(xtb + m.i00 + cc_);                                   \
        g[ch_][sg_][1] = *(const uint4*)(xtb + m.i01 + cc_);                                   \
        g[ch_][sg_][2] = *(const uint4*)(xtb + m.i10 + cc_);                                   \
        g[ch_][sg_][3] = *(const uint4*)(xtb + m.i11 + cc_);                                   \
      }                                                                                        \
    }                                                                                          \
    _Pragma("unroll") for (int i_ = 0; i_ < 16; ++i_) {                                        \
      const int idx_ = i_ * 256 + pt;            /* 0..4095, 16B each = 64KB */                \
      const int bch_ = idx_ >> 11;               /* chunk */                                   \
      const int c_ = idx_ & 2047;                                                             \
      const int row_ = c_ >> 3, slot_ = c_ & 7;                                               \
      const ushort_t* g_ =                                                                     \
          wb + ((TAP) << 16) + row_ * 256 + (C0) + bch_ * 64 + ((slot_ ^ (row_ & 7)) << 3);    \
      __builtin_amdgcn_global_load_lds((gvoid_t*)g_,                                           \
                                       (lvoid_t*)((char*)&Bbuf[(PB)][0][0] + idx_ * 16), 16,   \
                                       0, 0);                                                  \
    }                                                                                          \
    _Pragma("unroll") for (int ch_ = 0; ch_ < 2; ++ch_) {                                      \
      _Pragma("unroll") for (int sg_ = 0; sg_ < 2; ++sg_) {                                    \
        uint4 r;                                                                               \
        r.x = lerp_pack(g[ch_][sg_][0].x, g[ch_][sg_][1].x, g[ch_][sg_][2].x, g[ch_][sg_][3].x,\
                        m.w00, m.w01, m.w10, m.w11);                                           \
        r.y = lerp_pack(g[ch_][sg_][0].y, g[ch_][sg_][1].y, g[ch_][sg_][2].y, g[ch_][sg_][3].y,\
                        m.w00, m.w01, m.w10, m.w11);                                           \
        r.z = lerp_pack(g[ch_][sg_][0].z, g[ch_][sg_][1].z, g[ch_][sg_][2].z, g[ch_][sg_][3].z,\
                        m.w00, m.w01, m.w10, m.w11);                                           \
        r.w = lerp_pack(g[ch_][sg_][0].w, g[ch_][sg_][1].w, g[ch_][sg_][2].w, g[ch_][sg_][3].w,\
                        m.w00, m.w01, m.w10, m.w11);                                           \
        const int slice_ = c4 + sg_ * 4;                                                       \
        *(uint4*)&Abuf[(PB)][ch_][s_w * 64 + ((slice_ ^ (s_w & 7)) << 3)] = r;                 \
      }                                                                                        \
    }                                                                                          \
  }

  // ---- prologue: producers stage period 0 into pbuf 0 ----
  if (prod) {
    STAGE(0, 0, 0);
    VMWAIT(0);  // drain B(0) (and anything else) -> published at barrier
  }
  LGKM0;
  __builtin_amdgcn_s_barrier();

  // ---- main loop: 18 periods (period p: tap p>>1, C0 = (p&1)*128) ----
  #pragma unroll
  for (int p = 0; p < 18; ++p) {
    const int pb = p & 1;
    const int nb = pb ^ 1;
    if (prod) {
      // stage period p+1 while consumers compute period p
      if (p < 17) {
        const int tap1 = (p + 1) >> 1;
        const int c01 = ((p + 1) & 1) << 7;
        STAGE(tap1, c01, nb);
        VMWAIT(0);  // self-healing: retires own 16 B-loads + any spills
      }
    } else {
      // consumers: 4 K-steps of 32 over the 2 chunk sub-tiles, full BM
      #pragma unroll
      for (int ks = 0; ks < 4; ++ks) {
        const int ch = ks >> 1;
        const int kk = ks & 1;
        bf16x8 af[4], bfr[4];
        #pragma unroll
        for (int tm = 0; tm < 4; ++tm) {
          const int row = tm * 16 + wr;
          const int slot = (kk * 4 + wq) ^ (row & 7);
          af[tm] = *(const bf16x8*)&Abuf[pb][ch][row * 64 + slot * 8];
        }
        #pragma unroll
        for (int tn = 0; tn < 4; ++tn) {
          const int row = wn * 64 + tn * 16 + wr;
          const int slot = (kk * 4 + wq) ^ (row & 7);
          bfr[tn] = *(const bf16x8*)&Bbuf[pb][ch][row * 64 + slot * 8];
        }
        __builtin_amdgcn_s_setprio(1);
        #pragma unroll
        for (int tm = 0; tm < 4; ++tm)
          #pragma unroll
          for (int tn = 0; tn < 4; ++tn)
            acc[tm][tn] =
                __builtin_amdgcn_mfma_f32_16x16x32_bf16(af[tm], bfr[tn], acc[tm][tn], 0, 0, 0);
        __builtin_amdgcn_s_setprio(0);
      }
    }
    if (p < 17) {
      LGKM0;  // producers: A ds_writes done; consumers: ds_reads of pb done (WAR)
      __builtin_amdgcn_s_barrier();
    }
  }
#undef STAGE

  // ---- epilogue (consumers only): y write + fused GN partial stats ----
  if (!prod) {
    float* yb = y + ((size_t)(b * 4096 + h * 64)) * 256;
    #pragma unroll
    for (int tm = 0; tm < 4; ++tm) {
      #pragma unroll
      for (int tn = 0; tn < 4; ++tn) {
        const int o = wn * 64 + tn * 16 + wr;
        #pragma unroll
        for (int r2 = 0; r2 < 4; ++r2) {
          const int ww = tm * 16 + wq * 4 + r2;
          yb[ww * 256 + o] = acc[tm][tn][r2];
        }
      }
    }
    #pragma unroll
    for (int tn = 0; tn < 4; ++tn) {
      float sum = 0.f, ss = 0.f;
      #pragma unroll
      for (int tm = 0; tm < 4; ++tm)
        #pragma unroll
        for (int r2 = 0; r2 < 4; ++r2) {
          const float v = acc[tm][tn][r2];
          sum += v;
          ss += v * v;
        }
      sum += __shfl_xor(sum, 16, 64);
      ss += __shfl_xor(ss, 16, 64);
      sum += __shfl_xor(sum, 32, 64);
      ss += __shfl_xor(ss, 32, 64);
      #pragma unroll
      for (int d = 1; d < 8; d <<= 1) {
        sum += __shfl_xor(sum, d, 64);
        ss += __shfl_xor(ss, d, 64);
      }
      if (wq == 0 && (wr & 7) == 0) {
        const int gi = wn * 8 + tn * 2 + (wr >> 3);
        atomicAdd(&stats[(b * 32 + gi) * 2], sum);
        atomicAdd(&stats[(b * 32 + gi) * 2 + 1], ss);
      }
    }
  }
}

// ---------------- GN apply + ReLU, transpose [b][s][o] -> [b][o][s] ----------------
__global__ __launch_bounds__(256) void k_apply(const float* __restrict__ y,
                                               const float* __restrict__ stats,
                                               const float* __restrict__ gamma,
                                               const float* __restrict__ beta,
                                               float* __restrict__ out) {
  __shared__ float tile[64][65];
  __shared__ float sm[8], sr[8], sg[64], sb[64];
  const int bid = blockIdx.x;                    // 1024
  const int lb = ((bid & 7) << 7) | (bid >> 3);  // XCD-contiguous: same b region as k_gemm
  const int b = lb >> 8;
  const int st = (lb >> 2) & 63;
  const int ot = lb & 3;
  const int t = threadIdx.x;
  if (t < 8) {
    const int g = ot * 8 + t;
    const float s1 = stats[(b * 32 + g) * 2];
    const float s2 = stats[(b * 32 + g) * 2 + 1];
    const float mean = s1 * (1.f / 32768.f);
    const float var = s2 * (1.f / 32768.f) - mean * mean;
    sm[t] = mean;
    sr[t] = rsqrtf(var + 1e-5f);
  }
  if (t < 64) {
    sg[t] = gamma[ot * 64 + t];
    sb[t] = beta[ot * 64 + t];
  }
  const float* yb = y + ((size_t)(b * 4096 + st * 64)) * 256 + ot * 64;
  #pragma unroll
  for (int i = 0; i < 16; ++i) {
    const int idx = t + 256 * i;
    const int s_l = idx >> 6, o_l = idx & 63;
    tile[s_l][o_l] = yb[(size_t)s_l * 256 + o_l];
  }
  __syncthreads();
  float* ob = out + ((size_t)(b * 256 + ot * 64)) * 4096 + st * 64;
  #pragma unroll
  for (int i = 0; i < 16; ++i) {
    const int idx = t + 256 * i;
    const int o_l = idx >> 6, s_l = idx & 63;
    const int g = o_l >> 3;
    float v = (tile[s_l][o_l] - sm[g]) * sr[g] * sg[o_l] + sb[o_l];
    v = v > 0.f ? v : 0.f;
    ob[(size_t)o_l * 4096 + s_l] = v;
  }
}

extern "C" void kernel_launch(void* const* d_in, const int* in_sizes, int n_in,
                              void* d_out, int out_size, void* d_ws, size_t ws_size,
                              hipStream_t stream) {
  const float* x = (const float*)d_in[0];       // (4,256,64,64)
  const float* off = (const float*)d_in[1];     // (4,18,64,64)
  const float* w = (const float*)d_in[2];       // (256,256,3,3)
  const float* gamma = (const float*)d_in[3];   // (256)
  const float* beta = (const float*)d_in[4];    // (256)
  float* out = (float*)d_out;

  char* ws = (char*)d_ws;
  float* y = (float*)(ws);                        // 16,777,216 B  [b][s][o] f32
  ushort_t* xt = (ushort_t*)(ws + 16777216);      //  8,388,608 B  [b][h][w][c] bf16
  ushort_t* wb = (ushort_t*)(ws + 25165824);      //  1,179,648 B  [k][o][c] bf16
  float* stats = (float*)(ws + 26345472);         //      1,024 B  [b][g]{sum,ss}

  hipMemsetAsync(stats, 0, 1024, stream);
  k_prep_w<<<256, 256, 0, stream>>>(w, wb);
  k_prep_x<<<1024, 256, 0, stream>>>(x, xt);
  k_gemm<<<256, 512, 0, stream>>>(off, xt, wb, y, stats);
  k_apply<<<1024, 256, 0, stream>>>(y, stats, gamma, beta, out);
}